// Round 20
// baseline (280.922 us; speedup 1.0000x reference)
//
#include <hip/hip_runtime.h>
#include <hip/hip_bf16.h>

using bf16 = __hip_bfloat16;
typedef __attribute__((ext_vector_type(4))) float f32x4;
typedef __attribute__((ext_vector_type(8))) short short8;
typedef __attribute__((ext_vector_type(2))) unsigned int uint2v;
typedef __attribute__((ext_vector_type(4))) unsigned int uint4v;

#define DEVI static __device__ __forceinline__

DEVI unsigned short f2b(float f){
  unsigned int u = __float_as_uint(f);
  unsigned int r = (u + 0x7fffu + ((u >> 16) & 1u)) >> 16;
  return (unsigned short)r;
}
DEVI float b2f(unsigned short u){
  return __uint_as_float(((unsigned int)u) << 16);
}

DEVI void gload16(const void* g, void* l){
  __builtin_amdgcn_global_load_lds(
      (const __attribute__((address_space(1))) unsigned int*)g,
      (__attribute__((address_space(3))) unsigned int*)l, 16, 0, 0);
}

// ---- f32 -> bf16 convert for 3 equally-sized tensors packed into dst (wb only) ----
__global__ __launch_bounds__(256) void k_cvt3(const float* __restrict__ s0, const float* __restrict__ s1,
                                              const float* __restrict__ s2, bf16* __restrict__ dst, int n1)
{
  const size_t total = (size_t)3 * (size_t)n1 / 4;
  for (size_t i = (size_t)blockIdx.x*256 + threadIdx.x; i < total; i += (size_t)gridDim.x*256){
    const size_t e = i*4;
    const int which = (int)(e / (size_t)n1);
    const size_t off = e - (size_t)which*(size_t)n1;
    const float* s = which==0 ? s0 : which==1 ? s1 : s2;
    const f32x4 v = *reinterpret_cast<const f32x4*>(s + off);
    uint2v p;
    p[0] = (unsigned)f2b(v[0]) | ((unsigned)f2b(v[1])<<16);
    p[1] = (unsigned)f2b(v[2]) | ((unsigned)f2b(v[3])<<16);
    *reinterpret_cast<uint2v*>((unsigned short*)dst + e) = p;
  }
}

// ============================================================================
// k_front (R17 fusion, champion): gen (576) + transpose (4096) + pads (16)
// + b1 (1024) in one dispatch. gen blocks first (latency-bound long pole);
// short memory-bound blocks back-fill CU resources under gen's stalls.
// ============================================================================
__global__ __launch_bounds__(256, 3) void k_front(
    const float* __restrict__ x, bf16* __restrict__ xt, bf16* __restrict__ h1t,
    const float* __restrict__ att1f, const float* __restrict__ att2f,
    const float* __restrict__ att3f, const bf16* __restrict__ wbp,
    const float* __restrict__ bias0, const float* __restrict__ bias1,
    const float* __restrict__ bias2, bf16* __restrict__ Wt,
    const float* __restrict__ b1w, const float* __restrict__ b1b,
    float* __restrict__ b1out)
{
  __shared__ char sMem[49152];   // union: gen 48KB | transpose 16.6KB
  const int bid = blockIdx.x;
  const int tid = threadIdx.x;

  if (bid < 576){
    // ---------------- gen body (champion R8/R12) ----------------
    bf16* sAll = (bf16*)sMem;
    const int flat = bid;
    const int xcd = flat & 7, s = flat >> 3;          // s in [0,72)
    const int t = s % 3, u = s / 3;                   // u in [0,24)
    const int ch = u & 1;                             // c-half
    const int tau = (u >> 1)*8 + xcd;                 // [0,96)
    const int i = tau >> 5, boc = tau & 31;           // i [0,3), boc [0,32)
    const int bo0 = boc*128, c0 = ch*128;
    const bf16*  __restrict__ A  = wbp + (size_t)i*768*1024 + (size_t)(c0*3 + t)*1024;
    const float* __restrict__ Bf = ((i==0) ? att1f : (i==1) ? att2f : att3f) + (size_t)bo0*1024;
    const float* __restrict__ bias = (i==0) ? bias0 : (i==1) ? bias1 : bias2;
    const int lane = tid & 63, wid = tid >> 6;
    const int wr = wid >> 1, wc = wid & 1;            // 2 M-waves (c) x 2 N-waves (bo)
    const int frow = lane & 15, g = lane >> 4;
    f32x4 acc[4][4] = {};

#define GEN_STAGE(kt, bufi) { \
    _Pragma("unroll") \
    for (int j = 0; j < 2; ++j){ \
      const int q = tid + j*256, r = q >> 2, s3 = q & 3; \
      const int cc = (s3 ^ ((r >> 1) & 3)) * 8; \
      gload16(A + (size_t)r*3072 + (kt)*32 + cc, (char*)sAll + (bufi)*8192 + q*16); \
    } \
    _Pragma("unroll") \
    for (int j = 0; j < 4; ++j){ \
      const int q = tid + j*256, r = q >> 3, s7 = q & 7; \
      const int ss = s7 ^ (r & 7); \
      gload16(Bf + (size_t)r*1024 + (kt)*32 + ss*4, (char*)sAll + 16384 + (bufi)*16384 + q*16); \
    } \
  }

    GEN_STAGE(0, 0);
    #pragma unroll 1
    for (int kt = 0; kt < 32; ++kt){
      const int p = kt & 1;
      if (kt + 1 < 32){
        GEN_STAGE(kt+1, p^1);
        asm volatile("s_waitcnt vmcnt(6)" ::: "memory");   // drain tile kt only
      } else {
        asm volatile("s_waitcnt vmcnt(0)" ::: "memory");
      }
      __builtin_amdgcn_s_barrier();
      const char* pA = (const char*)sAll + p*8192;
      const char* pB = (const char*)sAll + 16384 + p*16384;
      short8 bfr[4];
      #pragma unroll
      for (int n = 0; n < 4; ++n){
        const int row = wc*64 + n*16 + frow;               // bo in [0,128)
        const f32x4 f0 = *reinterpret_cast<const f32x4*>(pB + row*128 + (((2*g)  ^ (row & 7))*16));
        const f32x4 f1 = *reinterpret_cast<const f32x4*>(pB + row*128 + (((2*g+1)^ (row & 7))*16));
        unsigned int w0, w1, w2, w3;
        asm("v_cvt_pk_bf16_f32 %0, %1, %2" : "=v"(w0) : "v"(f0[0]), "v"(f0[1]));
        asm("v_cvt_pk_bf16_f32 %0, %1, %2" : "=v"(w1) : "v"(f0[2]), "v"(f0[3]));
        asm("v_cvt_pk_bf16_f32 %0, %1, %2" : "=v"(w2) : "v"(f1[0]), "v"(f1[1]));
        asm("v_cvt_pk_bf16_f32 %0, %1, %2" : "=v"(w3) : "v"(f1[2]), "v"(f1[3]));
        union { uint4v u4; short8 sv; } cvtu;
        cvtu.u4[0] = w0; cvtu.u4[1] = w1; cvtu.u4[2] = w2; cvtu.u4[3] = w3;
        bfr[n] = cvtu.sv;
      }
      __builtin_amdgcn_s_setprio(1);
      #pragma unroll
      for (int m = 0; m < 4; ++m){
        const int row = wr*64 + m*16 + frow;               // c-local in [0,128)
        const int sl = g ^ ((row >> 1) & 3);
        const short8 af = *reinterpret_cast<const short8*>(pA + row*64 + sl*16);
        #pragma unroll
        for (int n = 0; n < 4; ++n)
          acc[m][n] = __builtin_amdgcn_mfma_f32_16x16x32_bf16(af, bfr[n], acc[m][n], 0, 0, 0);
      }
      __builtin_amdgcn_s_setprio(0);
      __builtin_amdgcn_s_barrier();
    }
#undef GEN_STAGE

    // epilogue: C-tile [128 bo][128 c] bf16 overlay; chunk^(row&15) swizzle.
    #pragma unroll
    for (int m = 0; m < 4; ++m){
      const int lcol = wr*64 + m*16 + g*4;                 // c-local
      float bi[4];
      #pragma unroll
      for (int j = 0; j < 4; ++j) bi[j] = bias[(c0 + lcol + j)*3 + t];
      #pragma unroll
      for (int n = 0; n < 4; ++n){
        const int row = wc*64 + n*16 + frow;               // bo-local in [0,128)
        uint2v pk;
        pk[0] = (unsigned)f2b(acc[m][n][0] + bi[0]) | ((unsigned)f2b(acc[m][n][1] + bi[1]) << 16);
        pk[1] = (unsigned)f2b(acc[m][n][2] + bi[2]) | ((unsigned)f2b(acc[m][n][3] + bi[3]) << 16);
        const int chunk = (lcol >> 3) ^ (row & 15);
        *reinterpret_cast<uint2v*>((char*)sAll + row*256 + chunk*16 + (g&1)*8) = pk;
      }
    }
    __syncthreads();
    {
      const int bb = boc >> 1, o0 = (boc & 1)*128;
      char* gp = (char*)Wt + 2*(((((size_t)(i*16 + bb)*3 + t)*256 + o0)*256) + c0);
      #pragma unroll
      for (int it = 0; it < 8; ++it){
        const int row = it*16 + (tid >> 4);                // o-local
        const int c = tid & 15;
        const int cs2 = c ^ (row & 15);
        const uint4v v = *reinterpret_cast<const uint4v*>((const char*)sAll + row*256 + cs2*16);
        *reinterpret_cast<uint4v*>(gp + (size_t)row*512 + c*16) = v;
      }
    }
    return;
  }

  if (bid < 4672){
    // ---------------- transpose body: x -> xT ----------------
    float (*tile)[65] = reinterpret_cast<float(*)[65]>(sMem);
    const int r2 = bid - 576;                  // [0,4096)
    const int b = r2 >> 8;                     // [0,16)
    const int rem = r2 & 255;
    const int c0 = ((rem >> 6) & 3)*64;        // [0,4)*64
    const int l0 = (rem & 63)*64;              // [0,64)*64
    {
      const int r = tid >> 2, q = tid & 3;
      const float* src = x + ((size_t)(b*256 + c0 + r))*4096 + l0 + q*16;
      #pragma unroll
      for (int j = 0; j < 4; ++j){
        const f32x4 v = *reinterpret_cast<const f32x4*>(src + j*4);
        #pragma unroll
        for (int e = 0; e < 4; ++e) tile[r][q*16 + j*4 + e] = v[e];
      }
    }
    __syncthreads();
    {
      const int jr = tid >> 2, cq = tid & 3;
      unsigned int w[8];
      #pragma unroll
      for (int e = 0; e < 8; ++e){
        const float lo = tile[cq*16 + 2*e][jr];
        const float hi = tile[cq*16 + 2*e + 1][jr];
        w[e] = (unsigned int)f2b(lo) | ((unsigned int)f2b(hi) << 16);
      }
      unsigned short* dst = (unsigned short*)xt + ((size_t)b*4098 + l0 + jr + 1)*256 + c0 + cq*16;
      uint4v a0 = {w[0],w[1],w[2],w[3]}, a1 = {w[4],w[5],w[6],w[7]};
      *reinterpret_cast<uint4v*>(dst)     = a0;
      *reinterpret_cast<uint4v*>(dst + 8) = a1;
    }
    return;
  }

  if (bid < 4688){
    // ---------------- zero pads of xT and h1T ----------------
    const int b = bid - 4672;
    const size_t top = (size_t)b*4098*256 + tid;
    const size_t bot = (size_t)b*4098*256 + (size_t)4097*256 + tid;
    unsigned short* px = (unsigned short*)xt;
    unsigned short* ph = (unsigned short*)h1t;
    px[top] = 0; px[bot] = 0; ph[top] = 0; ph[bot] = 0;
    return;
  }

  {
    // ---------------- b1 body ----------------
    const int m = (bid - 4688)*4 + (tid >> 6);
    const int lane = tid & 63;
    const float* a = att1f + (size_t)m*1024;
    float s = 0.f;
    for (int k = lane*4; k < 1024; k += 256){
      const f32x4 v = *reinterpret_cast<const f32x4*>(a + k);
      const f32x4 w = *reinterpret_cast<const f32x4*>(b1w + k);
      s += v[0]*w[0] + v[1]*w[1] + v[2]*w[2] + v[3]*w[3];
    }
    #pragma unroll
    for (int d = 32; d > 0; d >>= 1) s += __shfl_down(s, d);
    if (lane == 0) b1out[m] = s + b1b[0];
  }
}

// ============================================================================
// k_conv (R13 halo, champion): out = sum_t,c W*Xt. Tile 128o x 128l; 8
// c-steps of 32; all 3 taps from ONE 130-row halo B window per step.
// Lane-linear halo tail (rule #21). vmcnt(9), 2 blocks/CU.
// ============================================================================
__global__ __launch_bounds__(256, 2) void k_conv(const bf16* __restrict__ Xt, const bf16* __restrict__ W,
                                                 const float* __restrict__ bias, bf16* __restrict__ out,
                                                 int outBatchStride, int outRowOff, int applyRelu,
                                                 float* __restrict__ statSum, float* __restrict__ statSq)
{
  __shared__ char sAll[67584];   // A: 2x24576 @0 ; B: 2x9216 @49152 ; C-tile 32KB overlay @0
  const int flat = blockIdx.x + (blockIdx.z << 6);  // grid (64,1,16) -> [0,1024)
  const int xcd = flat & 7, s = flat >> 3;          // [0,128)
  const int b = 2*xcd + (s >> 6);
  const int rem = s & 63;
  const int oh = rem >> 5;                          // o-half: 0 or 1
  const int l0 = (rem & 31) * 128;
  const int tid = threadIdx.x, lane = tid & 63, wid = tid >> 6;
  const int wr = wid >> 1, wc = wid & 1;            // 2 o-waves x 2 l-waves
  const int frow = lane & 15, g = lane >> 4;
  f32x4 acc[4][4] = {};

#define CONV_STAGE(ct, bufi) { \
    const bf16* Ab = W + (((size_t)b*3)*256 + oh*128)*256 + (ct)*32; \
    _Pragma("unroll") \
    for (int t = 0; t < 3; ++t){ \
      _Pragma("unroll") \
      for (int j = 0; j < 2; ++j){ \
        const int q = tid + j*256, r = q >> 2; \
        const int cc = ((q & 3) ^ ((r >> 1) & 3)) * 8; \
        gload16(Ab + (size_t)t*65536 + (size_t)r*256 + cc, \
                sAll + (bufi)*24576 + t*8192 + q*16); \
      } \
    } \
    const bf16* Bb = Xt + ((size_t)b*4098 + l0)*256 + (ct)*32; \
    _Pragma("unroll") \
    for (int j = 0; j < 2; ++j){ \
      const int q = tid + j*256, r = q >> 2; \
      const int cc = ((q & 3) ^ ((r >> 1) & 3)) * 8; \
      gload16(Bb + (size_t)r*256 + cc, sAll + 49152 + (bufi)*9216 + q*16); \
    } \
    { /* halo tail: rows 128..129 (+pad), lane-linear, wave-duplicated */ \
      const int q = 512 + (tid & 63), r = q >> 2; \
      const int cc = ((q & 3) ^ ((r >> 1) & 3)) * 8; \
      gload16(Bb + (size_t)r*256 + cc, sAll + 49152 + (bufi)*9216 + q*16); \
    } \
  }

  CONV_STAGE(0, 0);
  #pragma unroll 1
  for (int ct = 0; ct < 8; ++ct){
    const int buf = ct & 1;
    if (ct + 1 < 8){
      CONV_STAGE(ct+1, buf^1);
      asm volatile("s_waitcnt vmcnt(9)" ::: "memory");   // drain step ct only
    } else {
      asm volatile("s_waitcnt vmcnt(0)" ::: "memory");
    }
    __builtin_amdgcn_s_barrier();
    const char* pA = sAll + buf*24576;
    const char* pB = sAll + 49152 + buf*9216;
    short8 afr[3][4], bfr[3][4];
    #pragma unroll
    for (int t = 0; t < 3; ++t){
      #pragma unroll
      for (int m = 0; m < 4; ++m){
        const int row = wr*64 + m*16 + frow;             // o-local in [0,128)
        const int sl = g ^ ((row >> 1) & 3);
        afr[t][m] = *reinterpret_cast<const short8*>(pA + t*8192 + row*64 + sl*16);
      }
      #pragma unroll
      for (int n = 0; n < 4; ++n){
        const int rl = wc*64 + n*16 + frow + t;          // halo row in [0,130)
        const int sl = g ^ ((rl >> 1) & 3);
        bfr[t][n] = *reinterpret_cast<const short8*>(pB + rl*64 + sl*16);
      }
    }
    __builtin_amdgcn_s_setprio(1);
    #pragma unroll
    for (int t = 0; t < 3; ++t)
      #pragma unroll
      for (int m = 0; m < 4; ++m)
        #pragma unroll
        for (int n = 0; n < 4; ++n)
          acc[m][n] = __builtin_amdgcn_mfma_f32_16x16x32_bf16(afr[t][m], bfr[t][n], acc[m][n], 0, 0, 0);
    __builtin_amdgcn_s_setprio(0);
    __builtin_amdgcn_s_barrier();
  }
#undef CONV_STAGE

  // epilogue: bias/relu/stats; acc -> swizzled LDS C-tile [128 l][128 o];
  // 256 B/row coalesced segments (2 full aligned lines, no WA fill).
  float cs[4][4] = {{0.f}}, cq[4][4] = {{0.f}};
  #pragma unroll
  for (int m = 0; m < 4; ++m){
    const int ol = wr*64 + m*16 + g*4;                   // o-local
    float bi[4] = {0.f, 0.f, 0.f, 0.f};
    if (bias){
      const f32x4 bv = *reinterpret_cast<const f32x4*>(bias + b*256 + oh*128 + ol);
      bi[0]=bv[0]; bi[1]=bv[1]; bi[2]=bv[2]; bi[3]=bv[3];
    }
    #pragma unroll
    for (int n = 0; n < 4; ++n){
      const int row = wc*64 + n*16 + frow;               // l-local
      float v[4];
      #pragma unroll
      for (int j = 0; j < 4; ++j){
        v[j] = acc[m][n][j] + bi[j];
        if (applyRelu) v[j] = fmaxf(v[j], 0.f);
        cs[m][j] += v[j];
        cq[m][j] += v[j]*v[j];
      }
      uint2v pk;
      pk[0] = (unsigned)f2b(v[0]) | ((unsigned)f2b(v[1]) << 16);
      pk[1] = (unsigned)f2b(v[2]) | ((unsigned)f2b(v[3]) << 16);
      const int chunk = (ol >> 3) ^ (row & 15);
      *reinterpret_cast<uint2v*>(sAll + row*256 + chunk*16 + (g&1)*8) = pk;
    }
  }
  __syncthreads();
  {
    char* gp = (char*)out + 2*((size_t)b*outBatchStride + (size_t)(l0 + outRowOff)*256 + oh*128);
    #pragma unroll
    for (int it = 0; it < 8; ++it){
      const int row = it*16 + (tid >> 4);
      const int c = tid & 15;
      const int cs2 = c ^ (row & 15);
      const uint4v v = *reinterpret_cast<const uint4v*>((const char*)sAll + row*256 + cs2*16);
      *reinterpret_cast<uint4v*>(gp + (size_t)row*512 + c*16) = v;
    }
  }
  if (statSum){
    #pragma unroll
    for (int m = 0; m < 4; ++m)
      #pragma unroll
      for (int j = 0; j < 4; ++j){
        #pragma unroll
        for (int d = 1; d < 16; d <<= 1){
          cs[m][j] += __shfl_xor(cs[m][j], d);
          cq[m][j] += __shfl_xor(cq[m][j], d);
        }
      }
    __syncthreads();                       // blast reads done -> LDS reusable
    float* ls = (float*)sAll;              // [4 waves][64 ch]
    float* lq = ls + 256;
    if (frow == 0){
      #pragma unroll
      for (int m = 0; m < 4; ++m)
        #pragma unroll
        for (int j = 0; j < 4; ++j){
          ls[wid*64 + m*16 + g*4 + j] = cs[m][j];
          lq[wid*64 + m*16 + g*4 + j] = cq[m][j];
        }
    }
    __syncthreads();
    if (tid < 128){
      const int ol = tid, wrI = ol >> 6, idx = ol & 63;
      const float sv = ls[(wrI*2 + 0)*64 + idx] + ls[(wrI*2 + 1)*64 + idx];
      const float qv = lq[(wrI*2 + 0)*64 + idx] + lq[(wrI*2 + 1)*64 + idx];
      atomicAdd(statSum + oh*128 + ol, sv);
      atomicAdd(statSq  + oh*128 + ol, qv);
    }
  }
}

// ---- h2T[b][lp][o] = relu(y2T[b][lp-1][o]*scale+shift), pads zeroed.
//      BN scale/shift computed INLINE per block from sum/sq (k_bnfin removed).
__global__ __launch_bounds__(256) void k_norm2(const bf16* __restrict__ y,
                                               const float* __restrict__ bnsum, const float* __restrict__ bnsq,
                                               const float* __restrict__ gw, const float* __restrict__ gb,
                                               bf16* __restrict__ h)
{
  __shared__ float scL[256], shL[256];
  {
    const int o = threadIdx.x;
    const float inv = 1.f/65536.f;
    const float m = bnsum[o]*inv;
    const float v = fmaxf(bnsq[o]*inv - m*m, 0.f);
    const float sc = gw[o] / sqrtf(v + 1e-5f);
    scL[o] = sc;
    shL[o] = gb[o] - m*sc;
  }
  __syncthreads();
  const int gr = blockIdx.x*8 + (threadIdx.x >> 5);
  const int oc = threadIdx.x & 31;
  const int b = gr / 4098, lp = gr - b*4098;
  unsigned short* dst = (unsigned short*)h + (size_t)gr*256 + oc*8;
  if (lp == 0 || lp == 4097){
    uint4v z = {0u,0u,0u,0u};
    *reinterpret_cast<uint4v*>(dst) = z;
    return;
  }
  const unsigned short* src = (const unsigned short*)y + ((size_t)b*4096 + (lp-1))*256 + oc*8;
  const uint4v in = *reinterpret_cast<const uint4v*>(src);
  const f32x4 sA0 = *reinterpret_cast<const f32x4*>(scL + oc*8);
  const f32x4 sA1 = *reinterpret_cast<const f32x4*>(scL + oc*8 + 4);
  const f32x4 hA0 = *reinterpret_cast<const f32x4*>(shL + oc*8);
  const f32x4 hA1 = *reinterpret_cast<const f32x4*>(shL + oc*8 + 4);
  uint4v ov;
  #pragma unroll
  for (int e = 0; e < 4; ++e){
    const unsigned int w = in[e];
    const float sc0 = (e<2) ? sA0[2*e] : sA1[2*e-4];
    const float sc1 = (e<2) ? sA0[2*e+1] : sA1[2*e-3];
    const float sh0 = (e<2) ? hA0[2*e] : hA1[2*e-4];
    const float sh1 = (e<2) ? hA0[2*e+1] : hA1[2*e-3];
    const float v0 = fmaxf(b2f((unsigned short)(w & 0xffffu))*sc0 + sh0, 0.f);
    const float v1 = fmaxf(b2f((unsigned short)(w >> 16))*sc1 + sh1, 0.f);
    ov[e] = (unsigned)f2b(v0) | ((unsigned)f2b(v1) << 16);
  }
  *reinterpret_cast<uint4v*>(dst) = ov;
}

// ---- stats-only pass for SE (BN3 affine inline): s_sum += sum_l relu(...) ----
__global__ __launch_bounds__(256) void k_sum3(const bf16* __restrict__ y,
                                              const float* __restrict__ bnsum, const float* __restrict__ bnsq,
                                              const float* __restrict__ gw, const float* __restrict__ gb,
                                              float* __restrict__ s_sum)
{
  __shared__ float red[8][256];
  __shared__ float scL[256], shL[256];
  const int tid = threadIdx.x;
  {
    const float inv = 1.f/65536.f;
    const float m = bnsum[tid]*inv;
    const float v = fmaxf(bnsq[tid]*inv - m*m, 0.f);
    const float sc = gw[tid] / sqrtf(v + 1e-5f);
    scL[tid] = sc;
    shL[tid] = gb[tid] - m*sc;
  }
  __syncthreads();
  const int rr = tid >> 5, oc = tid & 31;
  const size_t row = (size_t)blockIdx.x*8 + rr;
  const int b = (int)(row >> 12);
  const unsigned short* p = (const unsigned short*)y + row*256 + oc*8;
  const uint4v in = *reinterpret_cast<const uint4v*>(p);
  const f32x4 sA0 = *reinterpret_cast<const f32x4*>(scL + oc*8);
  const f32x4 sA1 = *reinterpret_cast<const f32x4*>(scL + oc*8 + 4);
  const f32x4 hA0 = *reinterpret_cast<const f32x4*>(shL + oc*8);
  const f32x4 hA1 = *reinterpret_cast<const f32x4*>(shL + oc*8 + 4);
  float loc[8];
  #pragma unroll
  for (int e = 0; e < 4; ++e){
    const unsigned int w = in[e];
    const float sc0 = (e<2) ? sA0[2*e] : sA1[2*e-4];
    const float sc1 = (e<2) ? sA0[2*e+1] : sA1[2*e-3];
    const float sh0 = (e<2) ? hA0[2*e] : hA1[2*e-4];
    const float sh1 = (e<2) ? hA0[2*e+1] : hA1[2*e-3];
    loc[2*e]   = fmaxf(b2f((unsigned short)(w & 0xffffu))*sc0 + sh0, 0.f);
    loc[2*e+1] = fmaxf(b2f((unsigned short)(w >> 16))*sc1 + sh1, 0.f);
  }
  #pragma unroll
  for (int j = 0; j < 8; ++j) red[rr][oc*8 + j] = loc[j];
  __syncthreads();
  const int o = tid;
  float tot = 0.f;
  #pragma unroll
  for (int r2 = 0; r2 < 8; ++r2) tot += red[r2][o];
  atomicAdd(&s_sum[(size_t)b*256 + o], tot);
}

// ---- SE: s2[b][o] = sigmoid(W2 @ relu(W1 @ mean + b1) + b2) ----
__global__ __launch_bounds__(256) void k_se(const float* __restrict__ s_sum, const float* __restrict__ w1,
                                            const float* __restrict__ b1, const float* __restrict__ w2,
                                            const float* __restrict__ b2, float* __restrict__ s2)
{
  __shared__ float sv[256];
  __shared__ float t1[256];
  const int b = blockIdx.x, o = threadIdx.x;
  sv[o] = s_sum[(size_t)b*256 + o] * (1.f/4096.f);
  __syncthreads();
  float a = b1[o];
  for (int c = 0; c < 256; ++c) a += w1[(size_t)o*256 + c] * sv[c];
  t1[o] = fmaxf(a, 0.f);
  __syncthreads();
  float a2 = b2[o];
  for (int c = 0; c < 256; ++c) a2 += w2[(size_t)o*256 + c] * t1[c];
  s2[(size_t)b*256 + o] = 1.f / (1.f + expf(-a2));
}

// ---- out[b][o][l] = relu( relu(y3*sc3+sh3)[l][o]*s2[b][o] + xT[l][o] )
//      BN3 scale/shift computed INLINE per block (k_bnfin removed). ----
__global__ __launch_bounds__(256) void k_final(const bf16* __restrict__ y3, const bf16* __restrict__ xt,
                                               const float* __restrict__ bnsum, const float* __restrict__ bnsq,
                                               const float* __restrict__ gw, const float* __restrict__ gb,
                                               const float* __restrict__ s2, float* __restrict__ out)
{
  __shared__ float tH[64][65];
  __shared__ float tX[64][65];
  __shared__ float scL[256], shL[256];
  const int b = blockIdx.z, o0 = blockIdx.y*64, l0 = blockIdx.x*64;
  const int tid = threadIdx.x;
  {
    const float inv = 1.f/65536.f;
    const float m = bnsum[tid]*inv;
    const float v = fmaxf(bnsq[tid]*inv - m*m, 0.f);
    const float sc = gw[tid] / sqrtf(v + 1e-5f);
    scL[tid] = sc;
    shL[tid] = gb[tid] - m*sc;
  }
  __syncthreads();
  {
    const int r = tid >> 2, q = tid & 3;
    const int cb = o0 + q*16;
    const unsigned short* sy = (const unsigned short*)y3 + ((size_t)b*4096 + l0 + r)*256 + cb;
    const unsigned short* sx = (const unsigned short*)xt + ((size_t)b*4098 + l0 + r + 1)*256 + cb;
    const uint4v y0 = *reinterpret_cast<const uint4v*>(sy);
    const uint4v y1 = *reinterpret_cast<const uint4v*>(sy + 8);
    const uint4v x0 = *reinterpret_cast<const uint4v*>(sx);
    const uint4v x1 = *reinterpret_cast<const uint4v*>(sx + 8);
    const f32x4 sc0 = *reinterpret_cast<const f32x4*>(scL + cb);
    const f32x4 sc1 = *reinterpret_cast<const f32x4*>(scL + cb + 4);
    const f32x4 sc2 = *reinterpret_cast<const f32x4*>(scL + cb + 8);
    const f32x4 sc3 = *reinterpret_cast<const f32x4*>(scL + cb + 12);
    const f32x4 sh0 = *reinterpret_cast<const f32x4*>(shL + cb);
    const f32x4 sh1 = *reinterpret_cast<const f32x4*>(shL + cb + 4);
    const f32x4 sh2 = *reinterpret_cast<const f32x4*>(shL + cb + 8);
    const f32x4 sh3 = *reinterpret_cast<const f32x4*>(shL + cb + 12);
    #pragma unroll
    for (int e = 0; e < 4; ++e){
      const float a0 = (e<2) ? sc0[2*e] : sc1[2*e-4];
      const float a1 = (e<2) ? sc0[2*e+1] : sc1[2*e-3];
      const float b0 = (e<2) ? sh0[2*e] : sh1[2*e-4];
      const float b1v = (e<2) ? sh0[2*e+1] : sh1[2*e-3];
      tH[r][q*16 + 2*e]     = fmaxf(b2f((unsigned short)(y0[e] & 0xffffu))*a0 + b0, 0.f);
      tH[r][q*16 + 2*e + 1] = fmaxf(b2f((unsigned short)(y0[e] >> 16))*a1 + b1v, 0.f);
      tX[r][q*16 + 2*e]     = b2f((unsigned short)(x0[e] & 0xffffu));
      tX[r][q*16 + 2*e + 1] = b2f((unsigned short)(x0[e] >> 16));
      const float c0v = (e<2) ? sc2[2*e] : sc3[2*e-4];
      const float c1v = (e<2) ? sc2[2*e+1] : sc3[2*e-3];
      const float d0 = (e<2) ? sh2[2*e] : sh3[2*e-4];
      const float d1 = (e<2) ? sh2[2*e+1] : sh3[2*e-3];
      tH[r][q*16 + 8 + 2*e]     = fmaxf(b2f((unsigned short)(y1[e] & 0xffffu))*c0v + d0, 0.f);
      tH[r][q*16 + 8 + 2*e + 1] = fmaxf(b2f((unsigned short)(y1[e] >> 16))*c1v + d1, 0.f);
      tX[r][q*16 + 8 + 2*e]     = b2f((unsigned short)(x1[e] & 0xffffu));
      tX[r][q*16 + 8 + 2*e + 1] = b2f((unsigned short)(x1[e] >> 16));
    }
  }
  __syncthreads();
  {
    const int orow = tid >> 2, q = tid & 3;
    const int o = o0 + orow;
    const float sfac = s2[(size_t)b*256 + o];
    float* dst = out + ((size_t)b*256 + o)*4096 + l0 + q*16;
    #pragma unroll
    for (int k = 0; k < 16; k += 4){
      f32x4 r;
      #pragma unroll
      for (int e = 0; e < 4; ++e)
        r[e] = fmaxf(tH[q*16 + k + e][orow]*sfac + tX[q*16 + k + e][orow], 0.f);
      *reinterpret_cast<f32x4*>(dst + k) = r;
    }
  }
}

extern "C" void kernel_launch(void* const* d_in, const int* in_sizes, int n_in,
                              void* d_out, int out_size, void* d_ws, size_t ws_size,
                              hipStream_t stream)
{
  const float* x     = (const float*)d_in[0];
  const float* att1  = (const float*)d_in[1];
  const float* att2  = (const float*)d_in[2];
  const float* att3  = (const float*)d_in[3];
  const float* w1_w  = (const float*)d_in[4];
  const float* w1_b  = (const float*)d_in[5];
  const float* w2_w  = (const float*)d_in[6];
  const float* w2_b  = (const float*)d_in[7];
  const float* w3_w  = (const float*)d_in[8];
  const float* w3_b  = (const float*)d_in[9];
  const float* b1_w  = (const float*)d_in[10];
  const float* b1_b  = (const float*)d_in[11];
  const float* bn2_w = (const float*)d_in[12];
  const float* bn2_b = (const float*)d_in[13];
  const float* bn3_w = (const float*)d_in[14];
  const float* bn3_b = (const float*)d_in[15];
  const float* se1_w = (const float*)d_in[16];
  const float* se1_b = (const float*)d_in[17];
  const float* se2_w = (const float*)d_in[18];
  const float* se2_b = (const float*)d_in[19];

  char* ws = (char*)d_ws;
  // workspace layout (bytes)
  bf16*  xT   = (bf16*)(ws + 0);           // [16][4098][256]  -- stays live for k_final
  bf16*  h1T  = (bf16*)(ws + 33570816);    // [16][4098][256]  -- reused as y3T after conv2
  bf16*  y2T  = (bf16*)(ws + 67141632);    // [16][4096][256]
  bf16*  h2T  = (bf16*)(ws + 100696064);   // [16][4098][256]
  bf16*  Wt   = (bf16*)(ws + 134266880);   // [3][16][3][256][256]
  bf16*  wb   = (bf16*)(ws + 178307072);   // [3][768][1024]
  float* b1v  = (float*)(ws + 183025664);  // [4096]
  float* st   = (float*)(ws + 183042048);
  float* bn2sum = st;          // 256
  float* bn2sq  = st + 256;
  float* bn3sum = st + 512;
  float* bn3sq  = st + 768;
  float* s_sum  = st + 1024;   // 4096
  float* s2v    = st + 6144;   // 4096
  bf16*  y3T  = (bf16*)(ws + 33570816);    // overlay on h1T (dead after conv2)

  // zero accumulators (bn2/bn3 sums + s_sum = 5120 floats)
  hipMemsetAsync(st, 0, 5120*sizeof(float), stream);

  k_cvt3<<<512,256,0,stream>>>(w1_w, w2_w, w3_w, wb, 768*1024);
  // fused front-end: gen (576) + transpose (4096) + zero_pads (16) + b1 (1024)
  k_front<<<5712,256,0,stream>>>(x, xT, h1T, att1, att2, att3, wb,
                                 w1_b, w2_b, w3_b, Wt, b1_w, b1_b, b1v);

  k_conv<<<dim3(64,1,16),256,0,stream>>>(xT,  Wt,                           b1v,     h1T, 4098*256, 1, 1, nullptr, nullptr);
  k_conv<<<dim3(64,1,16),256,0,stream>>>(h1T, Wt + (size_t)1*16*3*256*256,  nullptr, y2T, 4096*256, 0, 0, bn2sum, bn2sq);
  k_norm2<<<8196,256,0,stream>>>(y2T, bn2sum, bn2sq, bn2_w, bn2_b, h2T);
  k_conv<<<dim3(64,1,16),256,0,stream>>>(h2T, Wt + (size_t)2*16*3*256*256,  nullptr, y3T, 4096*256, 0, 0, bn3sum, bn3sq);
  k_sum3<<<8192,256,0,stream>>>(y3T, bn3sum, bn3sq, bn3_w, bn3_b, s_sum);
  k_se<<<16,256,0,stream>>>(s_sum, se1_w, se1_b, se2_w, se2_b, s2v);
  k_final<<<dim3(64,4,16),256,0,stream>>>(y3T, xT, bn3sum, bn3sq, bn3_w, bn3_b, s2v, (float*)d_out);
}

// Round 21
// 280.091 us; speedup vs baseline: 1.0030x; 1.0030x over previous
//
#include <hip/hip_runtime.h>
#include <hip/hip_bf16.h>

using bf16 = __hip_bfloat16;
typedef __attribute__((ext_vector_type(4))) float f32x4;
typedef __attribute__((ext_vector_type(8))) short short8;
typedef __attribute__((ext_vector_type(2))) unsigned int uint2v;
typedef __attribute__((ext_vector_type(4))) unsigned int uint4v;

#define DEVI static __device__ __forceinline__

DEVI unsigned short f2b(float f){
  unsigned int u = __float_as_uint(f);
  unsigned int r = (u + 0x7fffu + ((u >> 16) & 1u)) >> 16;
  return (unsigned short)r;
}
DEVI float b2f(unsigned short u){
  return __uint_as_float(((unsigned int)u) << 16);
}

DEVI void gload16(const void* g, void* l){
  __builtin_amdgcn_global_load_lds(
      (const __attribute__((address_space(1))) unsigned int*)g,
      (__attribute__((address_space(3))) unsigned int*)l, 16, 0, 0);
}

// ---- f32 -> bf16 convert for 3 equally-sized tensors packed into dst (wb only) ----
__global__ __launch_bounds__(256) void k_cvt3(const float* __restrict__ s0, const float* __restrict__ s1,
                                              const float* __restrict__ s2, bf16* __restrict__ dst, int n1)
{
  const size_t total = (size_t)3 * (size_t)n1 / 4;
  for (size_t i = (size_t)blockIdx.x*256 + threadIdx.x; i < total; i += (size_t)gridDim.x*256){
    const size_t e = i*4;
    const int which = (int)(e / (size_t)n1);
    const size_t off = e - (size_t)which*(size_t)n1;
    const float* s = which==0 ? s0 : which==1 ? s1 : s2;
    const f32x4 v = *reinterpret_cast<const f32x4*>(s + off);
    uint2v p;
    p[0] = (unsigned)f2b(v[0]) | ((unsigned)f2b(v[1])<<16);
    p[1] = (unsigned)f2b(v[2]) | ((unsigned)f2b(v[3])<<16);
    *reinterpret_cast<uint2v*>((unsigned short*)dst + e) = p;
  }
}

// ============================================================================
// k_front (R17 fusion, champion): gen (576) + transpose (4096) + pads (16)
// + b1 (1024) in one dispatch. gen blocks first (latency-bound long pole);
// short memory-bound blocks back-fill CU resources under gen's stalls.
// ============================================================================
__global__ __launch_bounds__(256, 3) void k_front(
    const float* __restrict__ x, bf16* __restrict__ xt, bf16* __restrict__ h1t,
    const float* __restrict__ att1f, const float* __restrict__ att2f,
    const float* __restrict__ att3f, const bf16* __restrict__ wbp,
    const float* __restrict__ bias0, const float* __restrict__ bias1,
    const float* __restrict__ bias2, bf16* __restrict__ Wt,
    const float* __restrict__ b1w, const float* __restrict__ b1b,
    float* __restrict__ b1out)
{
  __shared__ char sMem[49152];   // union: gen 48KB | transpose 16.6KB
  const int bid = blockIdx.x;
  const int tid = threadIdx.x;

  if (bid < 576){
    // ---------------- gen body (champion R8/R12) ----------------
    bf16* sAll = (bf16*)sMem;
    const int flat = bid;
    const int xcd = flat & 7, s = flat >> 3;          // s in [0,72)
    const int t = s % 3, u = s / 3;                   // u in [0,24)
    const int ch = u & 1;                             // c-half
    const int tau = (u >> 1)*8 + xcd;                 // [0,96)
    const int i = tau >> 5, boc = tau & 31;           // i [0,3), boc [0,32)
    const int bo0 = boc*128, c0 = ch*128;
    const bf16*  __restrict__ A  = wbp + (size_t)i*768*1024 + (size_t)(c0*3 + t)*1024;
    const float* __restrict__ Bf = ((i==0) ? att1f : (i==1) ? att2f : att3f) + (size_t)bo0*1024;
    const float* __restrict__ bias = (i==0) ? bias0 : (i==1) ? bias1 : bias2;
    const int lane = tid & 63, wid = tid >> 6;
    const int wr = wid >> 1, wc = wid & 1;            // 2 M-waves (c) x 2 N-waves (bo)
    const int frow = lane & 15, g = lane >> 4;
    f32x4 acc[4][4] = {};

#define GEN_STAGE(kt, bufi) { \
    _Pragma("unroll") \
    for (int j = 0; j < 2; ++j){ \
      const int q = tid + j*256, r = q >> 2, s3 = q & 3; \
      const int cc = (s3 ^ ((r >> 1) & 3)) * 8; \
      gload16(A + (size_t)r*3072 + (kt)*32 + cc, (char*)sAll + (bufi)*8192 + q*16); \
    } \
    _Pragma("unroll") \
    for (int j = 0; j < 4; ++j){ \
      const int q = tid + j*256, r = q >> 3, s7 = q & 7; \
      const int ss = s7 ^ (r & 7); \
      gload16(Bf + (size_t)r*1024 + (kt)*32 + ss*4, (char*)sAll + 16384 + (bufi)*16384 + q*16); \
    } \
  }

    GEN_STAGE(0, 0);
    #pragma unroll 1
    for (int kt = 0; kt < 32; ++kt){
      const int p = kt & 1;
      if (kt + 1 < 32){
        GEN_STAGE(kt+1, p^1);
        asm volatile("s_waitcnt vmcnt(6)" ::: "memory");   // drain tile kt only
      } else {
        asm volatile("s_waitcnt vmcnt(0)" ::: "memory");
      }
      __builtin_amdgcn_s_barrier();
      const char* pA = (const char*)sAll + p*8192;
      const char* pB = (const char*)sAll + 16384 + p*16384;
      short8 bfr[4];
      #pragma unroll
      for (int n = 0; n < 4; ++n){
        const int row = wc*64 + n*16 + frow;               // bo in [0,128)
        const f32x4 f0 = *reinterpret_cast<const f32x4*>(pB + row*128 + (((2*g)  ^ (row & 7))*16));
        const f32x4 f1 = *reinterpret_cast<const f32x4*>(pB + row*128 + (((2*g+1)^ (row & 7))*16));
        unsigned int w0, w1, w2, w3;
        asm("v_cvt_pk_bf16_f32 %0, %1, %2" : "=v"(w0) : "v"(f0[0]), "v"(f0[1]));
        asm("v_cvt_pk_bf16_f32 %0, %1, %2" : "=v"(w1) : "v"(f0[2]), "v"(f0[3]));
        asm("v_cvt_pk_bf16_f32 %0, %1, %2" : "=v"(w2) : "v"(f1[0]), "v"(f1[1]));
        asm("v_cvt_pk_bf16_f32 %0, %1, %2" : "=v"(w3) : "v"(f1[2]), "v"(f1[3]));
        union { uint4v u4; short8 sv; } cvtu;
        cvtu.u4[0] = w0; cvtu.u4[1] = w1; cvtu.u4[2] = w2; cvtu.u4[3] = w3;
        bfr[n] = cvtu.sv;
      }
      __builtin_amdgcn_s_setprio(1);
      #pragma unroll
      for (int m = 0; m < 4; ++m){
        const int row = wr*64 + m*16 + frow;               // c-local in [0,128)
        const int sl = g ^ ((row >> 1) & 3);
        const short8 af = *reinterpret_cast<const short8*>(pA + row*64 + sl*16);
        #pragma unroll
        for (int n = 0; n < 4; ++n)
          acc[m][n] = __builtin_amdgcn_mfma_f32_16x16x32_bf16(af, bfr[n], acc[m][n], 0, 0, 0);
      }
      __builtin_amdgcn_s_setprio(0);
      __builtin_amdgcn_s_barrier();
    }
#undef GEN_STAGE

    // epilogue: C-tile [128 bo][128 c] bf16 overlay; chunk^(row&15) swizzle.
    #pragma unroll
    for (int m = 0; m < 4; ++m){
      const int lcol = wr*64 + m*16 + g*4;                 // c-local
      float bi[4];
      #pragma unroll
      for (int j = 0; j < 4; ++j) bi[j] = bias[(c0 + lcol + j)*3 + t];
      #pragma unroll
      for (int n = 0; n < 4; ++n){
        const int row = wc*64 + n*16 + frow;               // bo-local in [0,128)
        uint2v pk;
        pk[0] = (unsigned)f2b(acc[m][n][0] + bi[0]) | ((unsigned)f2b(acc[m][n][1] + bi[1]) << 16);
        pk[1] = (unsigned)f2b(acc[m][n][2] + bi[2]) | ((unsigned)f2b(acc[m][n][3] + bi[3]) << 16);
        const int chunk = (lcol >> 3) ^ (row & 15);
        *reinterpret_cast<uint2v*>((char*)sAll + row*256 + chunk*16 + (g&1)*8) = pk;
      }
    }
    __syncthreads();
    {
      const int bb = boc >> 1, o0 = (boc & 1)*128;
      char* gp = (char*)Wt + 2*(((((size_t)(i*16 + bb)*3 + t)*256 + o0)*256) + c0);
      #pragma unroll
      for (int it = 0; it < 8; ++it){
        const int row = it*16 + (tid >> 4);                // o-local
        const int c = tid & 15;
        const int cs2 = c ^ (row & 15);
        const uint4v v = *reinterpret_cast<const uint4v*>((const char*)sAll + row*256 + cs2*16);
        *reinterpret_cast<uint4v*>(gp + (size_t)row*512 + c*16) = v;
      }
    }
    return;
  }

  if (bid < 4672){
    // ---------------- transpose body: x -> xT ----------------
    float (*tile)[65] = reinterpret_cast<float(*)[65]>(sMem);
    const int r2 = bid - 576;                  // [0,4096)
    const int b = r2 >> 8;                     // [0,16)
    const int rem = r2 & 255;
    const int c0 = ((rem >> 6) & 3)*64;        // [0,4)*64
    const int l0 = (rem & 63)*64;              // [0,64)*64
    {
      const int r = tid >> 2, q = tid & 3;
      const float* src = x + ((size_t)(b*256 + c0 + r))*4096 + l0 + q*16;
      #pragma unroll
      for (int j = 0; j < 4; ++j){
        const f32x4 v = *reinterpret_cast<const f32x4*>(src + j*4);
        #pragma unroll
        for (int e = 0; e < 4; ++e) tile[r][q*16 + j*4 + e] = v[e];
      }
    }
    __syncthreads();
    {
      const int jr = tid >> 2, cq = tid & 3;
      unsigned int w[8];
      #pragma unroll
      for (int e = 0; e < 8; ++e){
        const float lo = tile[cq*16 + 2*e][jr];
        const float hi = tile[cq*16 + 2*e + 1][jr];
        w[e] = (unsigned int)f2b(lo) | ((unsigned int)f2b(hi) << 16);
      }
      unsigned short* dst = (unsigned short*)xt + ((size_t)b*4098 + l0 + jr + 1)*256 + c0 + cq*16;
      uint4v a0 = {w[0],w[1],w[2],w[3]}, a1 = {w[4],w[5],w[6],w[7]};
      *reinterpret_cast<uint4v*>(dst)     = a0;
      *reinterpret_cast<uint4v*>(dst + 8) = a1;
    }
    return;
  }

  if (bid < 4688){
    // ---------------- zero pads of xT and h1T ----------------
    const int b = bid - 4672;
    const size_t top = (size_t)b*4098*256 + tid;
    const size_t bot = (size_t)b*4098*256 + (size_t)4097*256 + tid;
    unsigned short* px = (unsigned short*)xt;
    unsigned short* ph = (unsigned short*)h1t;
    px[top] = 0; px[bot] = 0; ph[top] = 0; ph[bot] = 0;
    return;
  }

  {
    // ---------------- b1 body ----------------
    const int m = (bid - 4688)*4 + (tid >> 6);
    const int lane = tid & 63;
    const float* a = att1f + (size_t)m*1024;
    float s = 0.f;
    for (int k = lane*4; k < 1024; k += 256){
      const f32x4 v = *reinterpret_cast<const f32x4*>(a + k);
      const f32x4 w = *reinterpret_cast<const f32x4*>(b1w + k);
      s += v[0]*w[0] + v[1]*w[1] + v[2]*w[2] + v[3]*w[3];
    }
    #pragma unroll
    for (int d = 32; d > 0; d >>= 1) s += __shfl_down(s, d);
    if (lane == 0) b1out[m] = s + b1b[0];
  }
}

// ============================================================================
// k_conv (R13 halo, champion): out = sum_t,c W*Xt. Tile 128o x 128l; 8
// c-steps of 32; all 3 taps from ONE 130-row halo B window per step.
// Lane-linear halo tail (rule #21). vmcnt(9), 2 blocks/CU.
// ============================================================================
__global__ __launch_bounds__(256, 2) void k_conv(const bf16* __restrict__ Xt, const bf16* __restrict__ W,
                                                 const float* __restrict__ bias, bf16* __restrict__ out,
                                                 int outBatchStride, int outRowOff, int applyRelu,
                                                 float* __restrict__ statSum, float* __restrict__ statSq)
{
  __shared__ char sAll[67584];   // A: 2x24576 @0 ; B: 2x9216 @49152 ; C-tile 32KB overlay @0
  const int flat = blockIdx.x + (blockIdx.z << 6);  // grid (64,1,16) -> [0,1024)
  const int xcd = flat & 7, s = flat >> 3;          // [0,128)
  const int b = 2*xcd + (s >> 6);
  const int rem = s & 63;
  const int oh = rem >> 5;                          // o-half: 0 or 1
  const int l0 = (rem & 31) * 128;
  const int tid = threadIdx.x, lane = tid & 63, wid = tid >> 6;
  const int wr = wid >> 1, wc = wid & 1;            // 2 o-waves x 2 l-waves
  const int frow = lane & 15, g = lane >> 4;
  f32x4 acc[4][4] = {};

#define CONV_STAGE(ct, bufi) { \
    const bf16* Ab = W + (((size_t)b*3)*256 + oh*128)*256 + (ct)*32; \
    _Pragma("unroll") \
    for (int t = 0; t < 3; ++t){ \
      _Pragma("unroll") \
      for (int j = 0; j < 2; ++j){ \
        const int q = tid + j*256, r = q >> 2; \
        const int cc = ((q & 3) ^ ((r >> 1) & 3)) * 8; \
        gload16(Ab + (size_t)t*65536 + (size_t)r*256 + cc, \
                sAll + (bufi)*24576 + t*8192 + q*16); \
      } \
    } \
    const bf16* Bb = Xt + ((size_t)b*4098 + l0)*256 + (ct)*32; \
    _Pragma("unroll") \
    for (int j = 0; j < 2; ++j){ \
      const int q = tid + j*256, r = q >> 2; \
      const int cc = ((q & 3) ^ ((r >> 1) & 3)) * 8; \
      gload16(Bb + (size_t)r*256 + cc, sAll + 49152 + (bufi)*9216 + q*16); \
    } \
    { /* halo tail: rows 128..129 (+pad), lane-linear, wave-duplicated */ \
      const int q = 512 + (tid & 63), r = q >> 2; \
      const int cc = ((q & 3) ^ ((r >> 1) & 3)) * 8; \
      gload16(Bb + (size_t)r*256 + cc, sAll + 49152 + (bufi)*9216 + q*16); \
    } \
  }

  CONV_STAGE(0, 0);
  #pragma unroll 1
  for (int ct = 0; ct < 8; ++ct){
    const int buf = ct & 1;
    if (ct + 1 < 8){
      CONV_STAGE(ct+1, buf^1);
      asm volatile("s_waitcnt vmcnt(9)" ::: "memory");   // drain step ct only
    } else {
      asm volatile("s_waitcnt vmcnt(0)" ::: "memory");
    }
    __builtin_amdgcn_s_barrier();
    const char* pA = sAll + buf*24576;
    const char* pB = sAll + 49152 + buf*9216;
    short8 afr[3][4], bfr[3][4];
    #pragma unroll
    for (int t = 0; t < 3; ++t){
      #pragma unroll
      for (int m = 0; m < 4; ++m){
        const int row = wr*64 + m*16 + frow;             // o-local in [0,128)
        const int sl = g ^ ((row >> 1) & 3);
        afr[t][m] = *reinterpret_cast<const short8*>(pA + t*8192 + row*64 + sl*16);
      }
      #pragma unroll
      for (int n = 0; n < 4; ++n){
        const int rl = wc*64 + n*16 + frow + t;          // halo row in [0,130)
        const int sl = g ^ ((rl >> 1) & 3);
        bfr[t][n] = *reinterpret_cast<const short8*>(pB + rl*64 + sl*16);
      }
    }
    __builtin_amdgcn_s_setprio(1);
    #pragma unroll
    for (int t = 0; t < 3; ++t)
      #pragma unroll
      for (int m = 0; m < 4; ++m)
        #pragma unroll
        for (int n = 0; n < 4; ++n)
          acc[m][n] = __builtin_amdgcn_mfma_f32_16x16x32_bf16(afr[t][m], bfr[t][n], acc[m][n], 0, 0, 0);
    __builtin_amdgcn_s_setprio(0);
    __builtin_amdgcn_s_barrier();
  }
#undef CONV_STAGE

  // epilogue: bias/relu/stats; acc -> swizzled LDS C-tile [128 l][128 o];
  // 256 B/row coalesced segments (2 full aligned lines, no WA fill).
  float cs[4][4] = {{0.f}}, cq[4][4] = {{0.f}};
  #pragma unroll
  for (int m = 0; m < 4; ++m){
    const int ol = wr*64 + m*16 + g*4;                   // o-local
    float bi[4] = {0.f, 0.f, 0.f, 0.f};
    if (bias){
      const f32x4 bv = *reinterpret_cast<const f32x4*>(bias + b*256 + oh*128 + ol);
      bi[0]=bv[0]; bi[1]=bv[1]; bi[2]=bv[2]; bi[3]=bv[3];
    }
    #pragma unroll
    for (int n = 0; n < 4; ++n){
      const int row = wc*64 + n*16 + frow;               // l-local
      float v[4];
      #pragma unroll
      for (int j = 0; j < 4; ++j){
        v[j] = acc[m][n][j] + bi[j];
        if (applyRelu) v[j] = fmaxf(v[j], 0.f);
        cs[m][j] += v[j];
        cq[m][j] += v[j]*v[j];
      }
      uint2v pk;
      pk[0] = (unsigned)f2b(v[0]) | ((unsigned)f2b(v[1]) << 16);
      pk[1] = (unsigned)f2b(v[2]) | ((unsigned)f2b(v[3]) << 16);
      const int chunk = (ol >> 3) ^ (row & 15);
      *reinterpret_cast<uint2v*>(sAll + row*256 + chunk*16 + (g&1)*8) = pk;
    }
  }
  __syncthreads();
  {
    char* gp = (char*)out + 2*((size_t)b*outBatchStride + (size_t)(l0 + outRowOff)*256 + oh*128);
    #pragma unroll
    for (int it = 0; it < 8; ++it){
      const int row = it*16 + (tid >> 4);
      const int c = tid & 15;
      const int cs2 = c ^ (row & 15);
      const uint4v v = *reinterpret_cast<const uint4v*>((const char*)sAll + row*256 + cs2*16);
      *reinterpret_cast<uint4v*>(gp + (size_t)row*512 + c*16) = v;
    }
  }
  if (statSum){
    #pragma unroll
    for (int m = 0; m < 4; ++m)
      #pragma unroll
      for (int j = 0; j < 4; ++j){
        #pragma unroll
        for (int d = 1; d < 16; d <<= 1){
          cs[m][j] += __shfl_xor(cs[m][j], d);
          cq[m][j] += __shfl_xor(cq[m][j], d);
        }
      }
    __syncthreads();                       // blast reads done -> LDS reusable
    float* ls = (float*)sAll;              // [4 waves][64 ch]
    float* lq = ls + 256;
    if (frow == 0){
      #pragma unroll
      for (int m = 0; m < 4; ++m)
        #pragma unroll
        for (int j = 0; j < 4; ++j){
          ls[wid*64 + m*16 + g*4 + j] = cs[m][j];
          lq[wid*64 + m*16 + g*4 + j] = cq[m][j];
        }
    }
    __syncthreads();
    if (tid < 128){
      const int ol = tid, wrI = ol >> 6, idx = ol & 63;
      const float sv = ls[(wrI*2 + 0)*64 + idx] + ls[(wrI*2 + 1)*64 + idx];
      const float qv = lq[(wrI*2 + 0)*64 + idx] + lq[(wrI*2 + 1)*64 + idx];
      atomicAdd(statSum + oh*128 + ol, sv);
      atomicAdd(statSq  + oh*128 + ol, qv);
    }
  }
}

// ---- h2T[b][lp][o] = relu(y2T[b][lp-1][o]*scale+shift), pads zeroed.
//      BN scale/shift computed INLINE per block from sum/sq (k_bnfin removed).
__global__ __launch_bounds__(256) void k_norm2(const bf16* __restrict__ y,
                                               const float* __restrict__ bnsum, const float* __restrict__ bnsq,
                                               const float* __restrict__ gw, const float* __restrict__ gb,
                                               bf16* __restrict__ h)
{
  __shared__ float scL[256], shL[256];
  {
    const int o = threadIdx.x;
    const float inv = 1.f/65536.f;
    const float m = bnsum[o]*inv;
    const float v = fmaxf(bnsq[o]*inv - m*m, 0.f);
    const float sc = gw[o] / sqrtf(v + 1e-5f);
    scL[o] = sc;
    shL[o] = gb[o] - m*sc;
  }
  __syncthreads();
  const int gr = blockIdx.x*8 + (threadIdx.x >> 5);
  const int oc = threadIdx.x & 31;
  const int b = gr / 4098, lp = gr - b*4098;
  unsigned short* dst = (unsigned short*)h + (size_t)gr*256 + oc*8;
  if (lp == 0 || lp == 4097){
    uint4v z = {0u,0u,0u,0u};
    *reinterpret_cast<uint4v*>(dst) = z;
    return;
  }
  const unsigned short* src = (const unsigned short*)y + ((size_t)b*4096 + (lp-1))*256 + oc*8;
  const uint4v in = *reinterpret_cast<const uint4v*>(src);
  const f32x4 sA0 = *reinterpret_cast<const f32x4*>(scL + oc*8);
  const f32x4 sA1 = *reinterpret_cast<const f32x4*>(scL + oc*8 + 4);
  const f32x4 hA0 = *reinterpret_cast<const f32x4*>(shL + oc*8);
  const f32x4 hA1 = *reinterpret_cast<const f32x4*>(shL + oc*8 + 4);
  uint4v ov;
  #pragma unroll
  for (int e = 0; e < 4; ++e){
    const unsigned int w = in[e];
    const float sc0 = (e<2) ? sA0[2*e] : sA1[2*e-4];
    const float sc1 = (e<2) ? sA0[2*e+1] : sA1[2*e-3];
    const float sh0 = (e<2) ? hA0[2*e] : hA1[2*e-4];
    const float sh1 = (e<2) ? hA0[2*e+1] : hA1[2*e-3];
    const float v0 = fmaxf(b2f((unsigned short)(w & 0xffffu))*sc0 + sh0, 0.f);
    const float v1 = fmaxf(b2f((unsigned short)(w >> 16))*sc1 + sh1, 0.f);
    ov[e] = (unsigned)f2b(v0) | ((unsigned)f2b(v1) << 16);
  }
  *reinterpret_cast<uint4v*>(dst) = ov;
}

// ---- stats-only pass for SE (BN3 affine inline): s_sum += sum_l relu(...) ----
__global__ __launch_bounds__(256) void k_sum3(const bf16* __restrict__ y,
                                              const float* __restrict__ bnsum, const float* __restrict__ bnsq,
                                              const float* __restrict__ gw, const float* __restrict__ gb,
                                              float* __restrict__ s_sum)
{
  __shared__ float red[8][256];
  __shared__ float scL[256], shL[256];
  const int tid = threadIdx.x;
  {
    const float inv = 1.f/65536.f;
    const float m = bnsum[tid]*inv;
    const float v = fmaxf(bnsq[tid]*inv - m*m, 0.f);
    const float sc = gw[tid] / sqrtf(v + 1e-5f);
    scL[tid] = sc;
    shL[tid] = gb[tid] - m*sc;
  }
  __syncthreads();
  const int rr = tid >> 5, oc = tid & 31;
  const size_t row = (size_t)blockIdx.x*8 + rr;
  const int b = (int)(row >> 12);
  const unsigned short* p = (const unsigned short*)y + row*256 + oc*8;
  const uint4v in = *reinterpret_cast<const uint4v*>(p);
  const f32x4 sA0 = *reinterpret_cast<const f32x4*>(scL + oc*8);
  const f32x4 sA1 = *reinterpret_cast<const f32x4*>(scL + oc*8 + 4);
  const f32x4 hA0 = *reinterpret_cast<const f32x4*>(shL + oc*8);
  const f32x4 hA1 = *reinterpret_cast<const f32x4*>(shL + oc*8 + 4);
  float loc[8];
  #pragma unroll
  for (int e = 0; e < 4; ++e){
    const unsigned int w = in[e];
    const float sc0 = (e<2) ? sA0[2*e] : sA1[2*e-4];
    const float sc1 = (e<2) ? sA0[2*e+1] : sA1[2*e-3];
    const float sh0 = (e<2) ? hA0[2*e] : hA1[2*e-4];
    const float sh1 = (e<2) ? hA0[2*e+1] : hA1[2*e-3];
    loc[2*e]   = fmaxf(b2f((unsigned short)(w & 0xffffu))*sc0 + sh0, 0.f);
    loc[2*e+1] = fmaxf(b2f((unsigned short)(w >> 16))*sc1 + sh1, 0.f);
  }
  #pragma unroll
  for (int j = 0; j < 8; ++j) red[rr][oc*8 + j] = loc[j];
  __syncthreads();
  const int o = tid;
  float tot = 0.f;
  #pragma unroll
  for (int r2 = 0; r2 < 8; ++r2) tot += red[r2][o];
  atomicAdd(&s_sum[(size_t)b*256 + o], tot);
}

// ---- SE: s2[b][o] = sigmoid(W2 @ relu(W1 @ mean + b1) + b2) ----
__global__ __launch_bounds__(256) void k_se(const float* __restrict__ s_sum, const float* __restrict__ w1,
                                            const float* __restrict__ b1, const float* __restrict__ w2,
                                            const float* __restrict__ b2, float* __restrict__ s2)
{
  __shared__ float sv[256];
  __shared__ float t1[256];
  const int b = blockIdx.x, o = threadIdx.x;
  sv[o] = s_sum[(size_t)b*256 + o] * (1.f/4096.f);
  __syncthreads();
  float a = b1[o];
  for (int c = 0; c < 256; ++c) a += w1[(size_t)o*256 + c] * sv[c];
  t1[o] = fmaxf(a, 0.f);
  __syncthreads();
  float a2 = b2[o];
  for (int c = 0; c < 256; ++c) a2 += w2[(size_t)o*256 + c] * t1[c];
  s2[(size_t)b*256 + o] = 1.f / (1.f + expf(-a2));
}

// ---- out[b][o][l] = relu( relu(y3*sc3+sh3)[l][o]*s2[b][o] + xT[l][o] )
//      BN3 scale/shift computed INLINE per block (k_bnfin removed). ----
__global__ __launch_bounds__(256) void k_final(const bf16* __restrict__ y3, const bf16* __restrict__ xt,
                                               const float* __restrict__ bnsum, const float* __restrict__ bnsq,
                                               const float* __restrict__ gw, const float* __restrict__ gb,
                                               const float* __restrict__ s2, float* __restrict__ out)
{
  __shared__ float tH[64][65];
  __shared__ float tX[64][65];
  __shared__ float scL[256], shL[256];
  const int b = blockIdx.z, o0 = blockIdx.y*64, l0 = blockIdx.x*64;
  const int tid = threadIdx.x;
  {
    const float inv = 1.f/65536.f;
    const float m = bnsum[tid]*inv;
    const float v = fmaxf(bnsq[tid]*inv - m*m, 0.f);
    const float sc = gw[tid] / sqrtf(v + 1e-5f);
    scL[tid] = sc;
    shL[tid] = gb[tid] - m*sc;
  }
  __syncthreads();
  {
    const int r = tid >> 2, q = tid & 3;
    const int cb = o0 + q*16;
    const unsigned short* sy = (const unsigned short*)y3 + ((size_t)b*4096 + l0 + r)*256 + cb;
    const unsigned short* sx = (const unsigned short*)xt + ((size_t)b*4098 + l0 + r + 1)*256 + cb;
    const uint4v y0 = *reinterpret_cast<const uint4v*>(sy);
    const uint4v y1 = *reinterpret_cast<const uint4v*>(sy + 8);
    const uint4v x0 = *reinterpret_cast<const uint4v*>(sx);
    const uint4v x1 = *reinterpret_cast<const uint4v*>(sx + 8);
    const f32x4 sc0 = *reinterpret_cast<const f32x4*>(scL + cb);
    const f32x4 sc1 = *reinterpret_cast<const f32x4*>(scL + cb + 4);
    const f32x4 sc2 = *reinterpret_cast<const f32x4*>(scL + cb + 8);
    const f32x4 sc3 = *reinterpret_cast<const f32x4*>(scL + cb + 12);
    const f32x4 sh0 = *reinterpret_cast<const f32x4*>(shL + cb);
    const f32x4 sh1 = *reinterpret_cast<const f32x4*>(shL + cb + 4);
    const f32x4 sh2 = *reinterpret_cast<const f32x4*>(shL + cb + 8);
    const f32x4 sh3 = *reinterpret_cast<const f32x4*>(shL + cb + 12);
    #pragma unroll
    for (int e = 0; e < 4; ++e){
      const float a0 = (e<2) ? sc0[2*e] : sc1[2*e-4];
      const float a1 = (e<2) ? sc0[2*e+1] : sc1[2*e-3];
      const float b0 = (e<2) ? sh0[2*e] : sh1[2*e-4];
      const float b1v = (e<2) ? sh0[2*e+1] : sh1[2*e-3];
      tH[r][q*16 + 2*e]     = fmaxf(b2f((unsigned short)(y0[e] & 0xffffu))*a0 + b0, 0.f);
      tH[r][q*16 + 2*e + 1] = fmaxf(b2f((unsigned short)(y0[e] >> 16))*a1 + b1v, 0.f);
      tX[r][q*16 + 2*e]     = b2f((unsigned short)(x0[e] & 0xffffu));
      tX[r][q*16 + 2*e + 1] = b2f((unsigned short)(x0[e] >> 16));
      const float c0v = (e<2) ? sc2[2*e] : sc3[2*e-4];
      const float c1v = (e<2) ? sc2[2*e+1] : sc3[2*e-3];
      const float d0 = (e<2) ? sh2[2*e] : sh3[2*e-4];
      const float d1 = (e<2) ? sh2[2*e+1] : sh3[2*e-3];
      tH[r][q*16 + 8 + 2*e]     = fmaxf(b2f((unsigned short)(y1[e] & 0xffffu))*c0v + d0, 0.f);
      tH[r][q*16 + 8 + 2*e + 1] = fmaxf(b2f((unsigned short)(y1[e] >> 16))*c1v + d1, 0.f);
      tX[r][q*16 + 8 + 2*e]     = b2f((unsigned short)(x1[e] & 0xffffu));
      tX[r][q*16 + 8 + 2*e + 1] = b2f((unsigned short)(x1[e] >> 16));
    }
  }
  __syncthreads();
  {
    const int orow = tid >> 2, q = tid & 3;
    const int o = o0 + orow;
    const float sfac = s2[(size_t)b*256 + o];
    float* dst = out + ((size_t)b*256 + o)*4096 + l0 + q*16;
    #pragma unroll
    for (int k = 0; k < 16; k += 4){
      f32x4 r;
      #pragma unroll
      for (int e = 0; e < 4; ++e)
        r[e] = fmaxf(tH[q*16 + k + e][orow]*sfac + tX[q*16 + k + e][orow], 0.f);
      *reinterpret_cast<f32x4*>(dst + k) = r;
    }
  }
}

extern "C" void kernel_launch(void* const* d_in, const int* in_sizes, int n_in,
                              void* d_out, int out_size, void* d_ws, size_t ws_size,
                              hipStream_t stream)
{
  const float* x     = (const float*)d_in[0];
  const float* att1  = (const float*)d_in[1];
  const float* att2  = (const float*)d_in[2];
  const float* att3  = (const float*)d_in[3];
  const float* w1_w  = (const float*)d_in[4];
  const float* w1_b  = (const float*)d_in[5];
  const float* w2_w  = (const float*)d_in[6];
  const float* w2_b  = (const float*)d_in[7];
  const float* w3_w  = (const float*)d_in[8];
  const float* w3_b  = (const float*)d_in[9];
  const float* b1_w  = (const float*)d_in[10];
  const float* b1_b  = (const float*)d_in[11];
  const float* bn2_w = (const float*)d_in[12];
  const float* bn2_b = (const float*)d_in[13];
  const float* bn3_w = (const float*)d_in[14];
  const float* bn3_b = (const float*)d_in[15];
  const float* se1_w = (const float*)d_in[16];
  const float* se1_b = (const float*)d_in[17];
  const float* se2_w = (const float*)d_in[18];
  const float* se2_b = (const float*)d_in[19];

  char* ws = (char*)d_ws;
  // workspace layout (bytes)
  bf16*  xT   = (bf16*)(ws + 0);           // [16][4098][256]  -- stays live for k_final
  bf16*  h1T  = (bf16*)(ws + 33570816);    // [16][4098][256]  -- reused as y3T after conv2
  bf16*  y2T  = (bf16*)(ws + 67141632);    // [16][4096][256]
  bf16*  h2T  = (bf16*)(ws + 100696064);   // [16][4098][256]
  bf16*  Wt   = (bf16*)(ws + 134266880);   // [3][16][3][256][256]
  bf16*  wb   = (bf16*)(ws + 178307072);   // [3][768][1024]
  float* b1v  = (float*)(ws + 183025664);  // [4096]
  float* st   = (float*)(ws + 183042048);
  float* bn2sum = st;          // 256
  float* bn2sq  = st + 256;
  float* bn3sum = st + 512;
  float* bn3sq  = st + 768;
  float* s_sum  = st + 1024;   // 4096
  float* s2v    = st + 6144;   // 4096
  bf16*  y3T  = (bf16*)(ws + 33570816);    // overlay on h1T (dead after conv2)

  // zero accumulators (bn2/bn3 sums + s_sum = 5120 floats)
  hipMemsetAsync(st, 0, 5120*sizeof(float), stream);

  k_cvt3<<<512,256,0,stream>>>(w1_w, w2_w, w3_w, wb, 768*1024);
  // fused front-end: gen (576) + transpose (4096) + zero_pads (16) + b1 (1024)
  k_front<<<5712,256,0,stream>>>(x, xT, h1T, att1, att2, att3, wb,
                                 w1_b, w2_b, w3_b, Wt, b1_w, b1_b, b1v);

  k_conv<<<dim3(64,1,16),256,0,stream>>>(xT,  Wt,                           b1v,     h1T, 4098*256, 1, 1, nullptr, nullptr);
  k_conv<<<dim3(64,1,16),256,0,stream>>>(h1T, Wt + (size_t)1*16*3*256*256,  nullptr, y2T, 4096*256, 0, 0, bn2sum, bn2sq);
  k_norm2<<<8196,256,0,stream>>>(y2T, bn2sum, bn2sq, bn2_w, bn2_b, h2T);
  k_conv<<<dim3(64,1,16),256,0,stream>>>(h2T, Wt + (size_t)2*16*3*256*256,  nullptr, y3T, 4096*256, 0, 0, bn3sum, bn3sq);
  k_sum3<<<8192,256,0,stream>>>(y3T, bn3sum, bn3sq, bn3_w, bn3_b, s_sum);
  k_se<<<16,256,0,stream>>>(s_sum, se1_w, se1_b, se2_w, se2_b, s2v);
  k_final<<<dim3(64,4,16),256,0,stream>>>(y3T, xT, bn3sum, bn3sq, bn3_w, bn3_b, s2v, (float*)d_out);
}